// Round 10
// baseline (100.288 us; speedup 1.0000x reference)
//
#include <hip/hip_runtime.h>

#define BLK 512
#define MT 32            // mfma tile edge
#define IA 2             // A-frags per wave
#define IB 512           // rows per block = 8 waves * 32 * IA
#define TJQ 512          // q points per LDS chunk
#define SJ 4             // j-slices per (dir,b) -> 512 blocks, one dispatch round

typedef __attribute__((ext_vector_type(8))) short short8;
typedef __attribute__((ext_vector_type(16))) float f32x16;

// Pin a tuple to arch VGPRs (gfx950 unified file).
#define FORCE_V(x) asm volatile("" : "+v"(x))

__device__ __forceinline__ unsigned int fmap(float f) {
  unsigned int b = __float_as_uint(f);
  return (b & 0x80000000u) ? ~b : (b | 0x80000000u);
}
__device__ __forceinline__ float funmap(unsigned int u) {
  return __uint_as_float((u & 0x80000000u) ? (u ^ 0x80000000u) : ~u);
}
__device__ __forceinline__ unsigned short f2bf(float f) {
  unsigned int u = __float_as_uint(f);
  u += 0x7FFFu + ((u >> 16) & 1u);
  return (unsigned short)(u >> 16);
}
__device__ __forceinline__ float bf2f(unsigned short h) {
  return __uint_as_float(((unsigned int)h) << 16);
}
__device__ __forceinline__ unsigned int pk(unsigned short a, unsigned short b) {
  return (unsigned int)a | ((unsigned int)b << 16);
}

union FragU { uint4 u; short8 s; };

__device__ __forceinline__ void conv_q(float qx, float qy, float qz,
                                       uint4& b0s, uint4& b1s) {
  unsigned short hx = f2bf(qx), hy = f2bf(qy), hz = f2bf(qz);
  unsigned short lx = f2bf(qx - bf2f(hx)), ly = f2bf(qy - bf2f(hy)),
                 lz = f2bf(qz - bf2f(hz));
  float nq = fmaf(qz, qz, fmaf(qy, qy, qx * qx));
  unsigned short nh = f2bf(nq);
  float r1 = nq - bf2f(nh);
  unsigned short nm = f2bf(r1);
  unsigned short nl = f2bf(r1 - bf2f(nm));
  b0s = make_uint4(pk(hx, hy), pk(hz, hx), pk(hy, hz), pk(lx, ly));
  b1s = make_uint4(pk(lz, lx), pk(ly, lz), pk(nh, nm), pk(nl, 0));
}

// D_ij = |q_j|^2 - 2 p_i.q_j via mfma_f32_32x32x16_bf16, split-bf16 compensated
// (k-slot layout verified R5-R9, absmax margin 0). R10: latency pipelining --
// (1) register B-prefetch one pair ahead of the MFMAs, (2) 4 MFMAs issued
// back-to-back before the min3 blocks, (3) double-buffered sB with ONE barrier
// per chunk (staging of ch+1 overlaps compute of ch).
__global__ __launch_bounds__(BLK, 2) void cl_mfma(
    const float* __restrict__ A, const float* __restrict__ Bp,
    unsigned int* __restrict__ umin, int N, int jslice, int Bn) {
  __shared__ uint4 sA[2][IB];        // 16 KB
  __shared__ uint4 sB[2][2][TJQ];    // [buf][g][point] 32 KB
  __shared__ float sNP[IB];          // 2 KB

  const int zi = blockIdx.z;
  const int dir = zi / Bn;
  const int b = zi - dir * Bn;
  const float* __restrict__ P = dir ? Bp : A;
  const float* __restrict__ Q = dir ? A : Bp;
  unsigned int* __restrict__ um = umin + ((size_t)dir * Bn + b) * N;

  const int t = threadIdx.x;
  const int ib0 = blockIdx.x * IB;
  const int jbase = blockIdx.y * jslice;
  const size_t boff = (size_t)b * 3 * N;
  const unsigned short one = 0x3F80u;  // bf16(1.0)

  // ---- stage A-vectors + |p|^2 ----
  {
    int i = ib0 + t;
    float x = P[boff + i], y = P[boff + N + i], zz = P[boff + 2 * N + i];
    float ax = -2.f * x, ay = -2.f * y, az = -2.f * zz;
    unsigned short hx = f2bf(ax), hy = f2bf(ay), hz = f2bf(az);
    unsigned short lx = f2bf(ax - bf2f(hx)), ly = f2bf(ay - bf2f(hy)),
                   lz = f2bf(az - bf2f(hz));
    sA[0][t] = make_uint4(pk(hx, hy), pk(hz, lx), pk(ly, lz), pk(hx, hy));
    sA[1][t] = make_uint4(pk(hz, lx), pk(ly, lz), pk(one, one), pk(one, 0));
    sNP[t] = fmaf(zz, zz, fmaf(y, y, x * x));
  }

  const int nch = jslice / TJQ;  // 8
  // stage chunk 0 into sB[0] and prefetch chunk 1's q
  float qx = Q[boff + jbase + t];
  float qy = Q[boff + N + jbase + t];
  float qz = Q[boff + 2 * N + jbase + t];
  {
    uint4 b0s, b1s;
    conv_q(qx, qy, qz, b0s, b1s);
    sB[0][0][t] = b0s;
    sB[0][1][t] = b1s;
  }
  {
    int j1 = jbase + (nch > 1 ? TJQ : 0) + t;
    qx = Q[boff + j1];
    qy = Q[boff + N + j1];
    qz = Q[boff + 2 * N + j1];
  }
  __syncthreads();  // sA + sB[0] ready

  const int w = t >> 6, l = t & 63, m = l & 31, g = l >> 5;
  FragU a0u, a1u;
  a0u.u = sA[g][w * (MT * IA) + m];
  a1u.u = sA[g][w * (MT * IA) + MT + m];
  const short8 af0 = a0u.s, af1 = a1u.s;

  float run0[16], run1[16];
  f32x16 zc;
#pragma unroll
  for (int r = 0; r < 16; ++r) { run0[r] = 3.0e38f; run1[r] = 3.0e38f; zc[r] = 0.0f; }
  FORCE_V(zc);

  for (int ch = 0; ch < nch; ++ch) {
    const int cur = ch & 1;
    // stage chunk ch+1 into the other buffer (overlaps compute below)
    if (ch + 1 < nch) {
      uint4 b0s, b1s;
      conv_q(qx, qy, qz, b0s, b1s);
      sB[cur ^ 1][0][t] = b0s;
      sB[cur ^ 1][1][t] = b1s;
      int jn = jbase + ((ch + 2 < nch) ? (ch + 2) : (ch + 1)) * TJQ + t;
      qx = Q[boff + jn];
      qy = Q[boff + N + jn];
      qz = Q[boff + 2 * N + jn];
    }

    // compute over sB[cur], register-prefetching one B-frag pair ahead
    FragU ba, bb, bna, bnb;
    ba.u = sB[cur][g][m];
    bb.u = sB[cur][g][MT + m];
#pragma unroll
    for (int jt = 0; jt < TJQ / MT; jt += 2) {
      if (jt + 2 < TJQ / MT) {
        bna.u = sB[cur][g][(jt + 2) * MT + m];
        bnb.u = sB[cur][g][(jt + 3) * MT + m];
      }
      f32x16 d0 = __builtin_amdgcn_mfma_f32_32x32x16_bf16(af0, ba.s, zc, 0, 0, 0);
      f32x16 d1 = __builtin_amdgcn_mfma_f32_32x32x16_bf16(af0, bb.s, zc, 0, 0, 0);
      f32x16 d2 = __builtin_amdgcn_mfma_f32_32x32x16_bf16(af1, ba.s, zc, 0, 0, 0);
      f32x16 d3 = __builtin_amdgcn_mfma_f32_32x32x16_bf16(af1, bb.s, zc, 0, 0, 0);
      FORCE_V(d0); FORCE_V(d1); FORCE_V(d2); FORCE_V(d3);
#pragma unroll
      for (int r = 0; r < 16; ++r)
        run0[r] = fminf(fminf(run0[r], d0[r]), d1[r]);  // v_min3_f32
#pragma unroll
      for (int r = 0; r < 16; ++r)
        run1[r] = fminf(fminf(run1[r], d2[r]), d3[r]);
      ba = bna;
      bb = bnb;
    }
    __syncthreads();  // sB[cur^1] staged AND sB[cur] fully consumed
  }

  // ---- epilogue: min across 32 cols, add |p|^2, atomicMin ----
  // C/D layout (m74/m101): col=lane&31, row=(reg&3)+8*(reg>>2)+4*(lane>>5)
#pragma unroll
  for (int r = 0; r < 16; ++r) {
    float v0 = run0[r], v1 = run1[r];
#pragma unroll
    for (int sh = 1; sh <= 16; sh <<= 1) {
      v0 = fminf(v0, __shfl_xor(v0, sh));
      v1 = fminf(v1, __shfl_xor(v1, sh));
    }
    if (m == 0) {
      int row = (r & 3) + 8 * (r >> 2) + 4 * g;
      int il0 = w * (MT * IA) + row;
      int il1 = il0 + MT;
      atomicMin(&um[ib0 + il0], fmap(v0 + sNP[il0]));
      atomicMin(&um[ib0 + il1], fmap(v1 + sNP[il1]));
    }
  }
}

// Parallel final reduce: u holds complete squared distances (256 KB).
__global__ __launch_bounds__(256) void cl_reduce(
    const unsigned int* __restrict__ u, float* __restrict__ out, int total) {
  const int t = threadIdx.x;
  const uint4* __restrict__ u4 = (const uint4*)u;
  const int n4 = total / 4;
  const int gid = blockIdx.x * 256 + t;
  const int gstride = gridDim.x * 256;
  double s = 0.0;
  for (int i = gid; i < n4; i += gstride) {
    uint4 v = u4[i];
    s += (double)funmap(v.x) + (double)funmap(v.y) +
         (double)funmap(v.z) + (double)funmap(v.w);
  }
  for (int off = 32; off > 0; off >>= 1) s += __shfl_down(s, off, 64);
  __shared__ double sw[4];
  if ((t & 63) == 0) sw[t >> 6] = s;
  __syncthreads();
  if (t == 0) {
    double tot = sw[0] + sw[1] + sw[2] + sw[3];
    atomicAdd(out, (float)(tot / (double)total));
  }
}

extern "C" void kernel_launch(void* const* d_in, const int* in_sizes, int n_in,
                              void* d_out, int out_size, void* d_ws, size_t ws_size,
                              hipStream_t stream) {
  const float* in_pc = (const float*)d_in[0];
  const float* tgt_pc = (const float*)d_in[1];
  const int B = 2, N = 16384;
  unsigned int* u = (unsigned int*)d_ws;  // [2][B][N] uints = 256 KB
  float* out = (float*)d_out;

  hipMemsetAsync(u, 0xFF, (size_t)2 * B * N * sizeof(unsigned int), stream);
  hipMemsetAsync(out, 0, sizeof(float), stream);

  const int jslice = N / SJ;             // 4096
  dim3 grid(N / IB, SJ, 2 * B);          // (32,4,4) = 512 blocks x 512 thr
  cl_mfma<<<grid, dim3(BLK), 0, stream>>>(in_pc, tgt_pc, u, N, jslice, B);

  const int total = 2 * B * N;
  cl_reduce<<<dim3(16), dim3(256), 0, stream>>>(u, out, total);
}

// Round 11
// 99.733 us; speedup vs baseline: 1.0056x; 1.0056x over previous
//
#include <hip/hip_runtime.h>

#define BLK 512
#define MT 32            // mfma tile edge
#define IA 2             // A-frags per wave
#define IB 512           // rows per block = 8 waves * 32 * IA
#define TJQ 512          // q points per LDS chunk
#define SJ 4             // j-slices per (dir,b) -> 512 blocks, one dispatch round

typedef __attribute__((ext_vector_type(8))) short short8;
typedef __attribute__((ext_vector_type(16))) float f32x16;

__device__ __forceinline__ unsigned int fmap(float f) {
  unsigned int b = __float_as_uint(f);
  return (b & 0x80000000u) ? ~b : (b | 0x80000000u);
}
__device__ __forceinline__ float funmap(unsigned int u) {
  return __uint_as_float((u & 0x80000000u) ? (u ^ 0x80000000u) : ~u);
}
__device__ __forceinline__ unsigned short f2bf(float f) {
  unsigned int u = __float_as_uint(f);
  u += 0x7FFFu + ((u >> 16) & 1u);
  return (unsigned short)(u >> 16);
}
__device__ __forceinline__ float bf2f(unsigned short h) {
  return __uint_as_float(((unsigned int)h) << 16);
}
__device__ __forceinline__ unsigned int pk(unsigned short a, unsigned short b) {
  return (unsigned int)a | ((unsigned int)b << 16);
}

union FragU { uint4 u; short8 s; };

// Two MFMAs into VGPR destinations (inline asm "=&v" -> arch VGPRs on the
// gfx950 unified file; the intrinsic always picks AGPRs + per-use copies,
// which was 33K VALU-cyc/SIMD in R9/R10). s_nop 7,7,1 = 18 cyc covers the
// 16-pass MFMA D-write -> VALU-read hazard (compiler can't see into asm).
#define MFMA2(d0, d1, a, b0, b1, c)                                    \
  asm("v_mfma_f32_32x32x16_bf16 %0, %2, %3, %5\n\t"                    \
      "v_mfma_f32_32x32x16_bf16 %1, %2, %4, %5\n\t"                    \
      "s_nop 7\n\t"                                                    \
      "s_nop 7\n\t"                                                    \
      "s_nop 1"                                                        \
      : "=&v"(d0), "=&v"(d1)                                           \
      : "v"(a), "v"(b0), "v"(b1), "v"(c))

// D_ij = |q_j|^2 - 2 p_i.q_j via split-bf16-compensated MFMA (k-slot layout
// verified R5-R10, absmax margin 0). R11: VGPR-dest MFMA, copy-free min3.
__global__ __launch_bounds__(BLK, 2) void cl_mfma(
    const float* __restrict__ A, const float* __restrict__ Bp,
    unsigned int* __restrict__ umin, int N, int jslice, int Bn) {
  __shared__ uint4 sA[2][IB];   // A-vec halves [g][row]
  __shared__ uint4 sB[2][TJQ];  // B-vec halves [g][point]
  __shared__ float sNP[IB];     // |p|^2 per row

  const int zi = blockIdx.z;
  const int dir = zi / Bn;
  const int b = zi - dir * Bn;
  const float* __restrict__ P = dir ? Bp : A;
  const float* __restrict__ Q = dir ? A : Bp;
  unsigned int* __restrict__ um = umin + ((size_t)dir * Bn + b) * N;

  const int t = threadIdx.x;
  const int ib0 = blockIdx.x * IB;
  const int jbase = blockIdx.y * jslice;
  const size_t boff = (size_t)b * 3 * N;
  const unsigned short one = 0x3F80u;  // bf16(1.0)

  // ---- stage A-vectors + |p|^2 (once) ----
  {
    int i = ib0 + t;
    float x = P[boff + i], y = P[boff + N + i], zz = P[boff + 2 * N + i];
    float ax = -2.f * x, ay = -2.f * y, az = -2.f * zz;
    unsigned short hx = f2bf(ax), hy = f2bf(ay), hz = f2bf(az);
    unsigned short lx = f2bf(ax - bf2f(hx)), ly = f2bf(ay - bf2f(hy)),
                   lz = f2bf(az - bf2f(hz));
    sA[0][t] = make_uint4(pk(hx, hy), pk(hz, lx), pk(ly, lz), pk(hx, hy));
    sA[1][t] = make_uint4(pk(hz, lx), pk(ly, lz), pk(one, one), pk(one, 0));
    sNP[t] = fmaf(zz, zz, fmaf(y, y, x * x));
  }
  __syncthreads();

  const int w = t >> 6, l = t & 63, m = l & 31, g = l >> 5;
  FragU a0u, a1u;
  a0u.u = sA[g][w * (MT * IA) + m];        // rows w*64 + 0..31
  a1u.u = sA[g][w * (MT * IA) + MT + m];   // rows w*64 + 32..63
  const short8 af0 = a0u.s, af1 = a1u.s;

  float run0[16], run1[16];
  f32x16 zc;
#pragma unroll
  for (int r = 0; r < 16; ++r) { run0[r] = 3.0e38f; run1[r] = 3.0e38f; zc[r] = 0.0f; }

  const int nch = jslice / TJQ;  // 8
  float qx = Q[boff + jbase + t];
  float qy = Q[boff + N + jbase + t];
  float qz = Q[boff + 2 * N + jbase + t];

  for (int ch = 0; ch < nch; ++ch) {
    unsigned short hx = f2bf(qx), hy = f2bf(qy), hz = f2bf(qz);
    unsigned short lx = f2bf(qx - bf2f(hx)), ly = f2bf(qy - bf2f(hy)),
                   lz = f2bf(qz - bf2f(hz));
    float nq = fmaf(qz, qz, fmaf(qy, qy, qx * qx));
    unsigned short nh = f2bf(nq);
    float r1 = nq - bf2f(nh);
    unsigned short nm = f2bf(r1);
    unsigned short nl = f2bf(r1 - bf2f(nm));
    uint4 b0s = make_uint4(pk(hx, hy), pk(hz, hx), pk(hy, hz), pk(lx, ly));
    uint4 b1s = make_uint4(pk(lz, lx), pk(ly, lz), pk(nh, nm), pk(nl, 0));

    __syncthreads();  // previous chunk fully consumed
    sB[0][t] = b0s;
    sB[1][t] = b1s;
    {  // prefetch next chunk's q
      int jn = (ch + 1 < nch) ? (jbase + (ch + 1) * TJQ + t) : (jbase + t);
      qx = Q[boff + jn];
      qy = Q[boff + N + jn];
      qz = Q[boff + 2 * N + jn];
    }
    __syncthreads();

#pragma unroll
    for (int jt = 0; jt < TJQ / MT; jt += 2) {
      FragU ba, bb;
      ba.u = sB[g][(jt + 0) * MT + m];
      bb.u = sB[g][(jt + 1) * MT + m];
      f32x16 d0, d1;
      MFMA2(d0, d1, af0, ba.s, bb.s, zc);
#pragma unroll
      for (int r = 0; r < 16; ++r)
        run0[r] = fminf(fminf(run0[r], d0[r]), d1[r]);  // v_min3_f32, VGPR srcs
      f32x16 d2, d3;
      MFMA2(d2, d3, af1, ba.s, bb.s, zc);
#pragma unroll
      for (int r = 0; r < 16; ++r)
        run1[r] = fminf(fminf(run1[r], d2[r]), d3[r]);
    }
  }

  // ---- epilogue: min across 32 cols, add |p|^2, atomicMin ----
  // C/D layout (m74/m101): col=lane&31, row=(reg&3)+8*(reg>>2)+4*(lane>>5)
#pragma unroll
  for (int r = 0; r < 16; ++r) {
    float v0 = run0[r], v1 = run1[r];
#pragma unroll
    for (int sh = 1; sh <= 16; sh <<= 1) {
      v0 = fminf(v0, __shfl_xor(v0, sh));
      v1 = fminf(v1, __shfl_xor(v1, sh));
    }
    if (m == 0) {
      int row = (r & 3) + 8 * (r >> 2) + 4 * g;
      int il0 = w * (MT * IA) + row;
      int il1 = il0 + MT;
      atomicMin(&um[ib0 + il0], fmap(v0 + sNP[il0]));
      atomicMin(&um[ib0 + il1], fmap(v1 + sNP[il1]));
    }
  }
}

// Parallel final reduce: u holds complete squared distances (256 KB).
__global__ __launch_bounds__(256) void cl_reduce(
    const unsigned int* __restrict__ u, float* __restrict__ out, int total) {
  const int t = threadIdx.x;
  const uint4* __restrict__ u4 = (const uint4*)u;
  const int n4 = total / 4;
  const int gid = blockIdx.x * 256 + t;
  const int gstride = gridDim.x * 256;
  double s = 0.0;
  for (int i = gid; i < n4; i += gstride) {
    uint4 v = u4[i];
    s += (double)funmap(v.x) + (double)funmap(v.y) +
         (double)funmap(v.z) + (double)funmap(v.w);
  }
  for (int off = 32; off > 0; off >>= 1) s += __shfl_down(s, off, 64);
  __shared__ double sw[4];
  if ((t & 63) == 0) sw[t >> 6] = s;
  __syncthreads();
  if (t == 0) {
    double tot = sw[0] + sw[1] + sw[2] + sw[3];
    atomicAdd(out, (float)(tot / (double)total));
  }
}

extern "C" void kernel_launch(void* const* d_in, const int* in_sizes, int n_in,
                              void* d_out, int out_size, void* d_ws, size_t ws_size,
                              hipStream_t stream) {
  const float* in_pc = (const float*)d_in[0];
  const float* tgt_pc = (const float*)d_in[1];
  const int B = 2, N = 16384;
  unsigned int* u = (unsigned int*)d_ws;  // [2][B][N] uints = 256 KB
  float* out = (float*)d_out;

  hipMemsetAsync(u, 0xFF, (size_t)2 * B * N * sizeof(unsigned int), stream);
  hipMemsetAsync(out, 0, sizeof(float), stream);

  const int jslice = N / SJ;             // 4096
  dim3 grid(N / IB, SJ, 2 * B);          // (32,4,4) = 512 blocks x 512 thr
  cl_mfma<<<grid, dim3(BLK), 0, stream>>>(in_pc, tgt_pc, u, N, jslice, B);

  const int total = 2 * B * N;
  cl_reduce<<<dim3(16), dim3(256), 0, stream>>>(u, out, total);
}

// Round 12
// 98.500 us; speedup vs baseline: 1.0181x; 1.0125x over previous
//
#include <hip/hip_runtime.h>

#define BLK 512
#define MT 32            // mfma tile edge
#define IA 2             // A-frags per wave
#define IB 512           // rows per block = 8 waves * 32 * IA
#define TJQ 512          // q points per LDS chunk
#define SJ 4             // j-slices per (dir,b) -> 512 blocks, one dispatch round

typedef __attribute__((ext_vector_type(8))) short short8;
typedef __attribute__((ext_vector_type(16))) float f32x16;

__device__ __forceinline__ unsigned int fmap(float f) {
  unsigned int b = __float_as_uint(f);
  return (b & 0x80000000u) ? ~b : (b | 0x80000000u);
}
__device__ __forceinline__ float funmap(unsigned int u) {
  return __uint_as_float((u & 0x80000000u) ? (u ^ 0x80000000u) : ~u);
}
__device__ __forceinline__ unsigned short f2bf(float f) {
  unsigned int u = __float_as_uint(f);
  u += 0x7FFFu + ((u >> 16) & 1u);
  return (unsigned short)(u >> 16);
}
__device__ __forceinline__ float bf2f(unsigned short h) {
  return __uint_as_float(((unsigned int)h) << 16);
}
__device__ __forceinline__ unsigned int pk(unsigned short a, unsigned short b) {
  return (unsigned int)a | ((unsigned int)b << 16);
}

union FragU { uint4 u; short8 s; };

// Two MFMAs into VGPR destinations ("=&v" on the gfx950 unified file).
// s_nop 7,7,1 = 18 cyc covers MFMA D-write -> VALU-read (validated R11,
// absmax margin 0).
#define MFMA2(d0, d1, a, b0, b1, c)                                    \
  asm("v_mfma_f32_32x32x16_bf16 %0, %2, %3, %5\n\t"                    \
      "v_mfma_f32_32x32x16_bf16 %1, %2, %4, %5\n\t"                    \
      "s_nop 7\n\t"                                                    \
      "s_nop 7\n\t"                                                    \
      "s_nop 1"                                                        \
      : "=&v"(d0), "=&v"(d1)                                           \
      : "v"(a), "v"(b0), "v"(b1), "v"(c))

// v_min3 with ALL operands pinned to arch VGPRs. R11's counter arithmetic
// showed run0/run1 were allocated to AGPRs (VGPR_Count=60) and every fminf
// paid a<->v copies (~33K cyc/SIMD = the whole remaining overhead). "+v" at
// every use makes v-residency the allocator's zero-copy solution.
#define MIN3(acc, x, y)                                                \
  asm("v_min3_f32 %0, %0, %1, %2" : "+v"(acc) : "v"(x), "v"(y))

// D_ij = |q_j|^2 - 2 p_i.q_j via split-bf16-compensated MFMA (k-slot layout
// verified R5-R11, absmax margin 0). R12: copy-free accumulators.
__global__ __launch_bounds__(BLK, 4) void cl_mfma(
    const float* __restrict__ A, const float* __restrict__ Bp,
    unsigned int* __restrict__ umin, int N, int jslice, int Bn) {
  __shared__ uint4 sA[2][IB];   // A-vec halves [g][row]
  __shared__ uint4 sB[2][TJQ];  // B-vec halves [g][point]
  __shared__ float sNP[IB];     // |p|^2 per row

  const int zi = blockIdx.z;
  const int dir = zi / Bn;
  const int b = zi - dir * Bn;
  const float* __restrict__ P = dir ? Bp : A;
  const float* __restrict__ Q = dir ? A : Bp;
  unsigned int* __restrict__ um = umin + ((size_t)dir * Bn + b) * N;

  const int t = threadIdx.x;
  const int ib0 = blockIdx.x * IB;
  const int jbase = blockIdx.y * jslice;
  const size_t boff = (size_t)b * 3 * N;
  const unsigned short one = 0x3F80u;  // bf16(1.0)

  // ---- stage A-vectors + |p|^2 (once) ----
  {
    int i = ib0 + t;
    float x = P[boff + i], y = P[boff + N + i], zz = P[boff + 2 * N + i];
    float ax = -2.f * x, ay = -2.f * y, az = -2.f * zz;
    unsigned short hx = f2bf(ax), hy = f2bf(ay), hz = f2bf(az);
    unsigned short lx = f2bf(ax - bf2f(hx)), ly = f2bf(ay - bf2f(hy)),
                   lz = f2bf(az - bf2f(hz));
    sA[0][t] = make_uint4(pk(hx, hy), pk(hz, lx), pk(ly, lz), pk(hx, hy));
    sA[1][t] = make_uint4(pk(hz, lx), pk(ly, lz), pk(one, one), pk(one, 0));
    sNP[t] = fmaf(zz, zz, fmaf(y, y, x * x));
  }
  __syncthreads();

  const int w = t >> 6, l = t & 63, m = l & 31, g = l >> 5;
  FragU a0u, a1u;
  a0u.u = sA[g][w * (MT * IA) + m];        // rows w*64 + 0..31
  a1u.u = sA[g][w * (MT * IA) + MT + m];   // rows w*64 + 32..63
  const short8 af0 = a0u.s, af1 = a1u.s;

  float run0[16], run1[16];
  f32x16 zc;
#pragma unroll
  for (int r = 0; r < 16; ++r) { run0[r] = 3.0e38f; run1[r] = 3.0e38f; zc[r] = 0.0f; }

  const int nch = jslice / TJQ;  // 8
  float qx = Q[boff + jbase + t];
  float qy = Q[boff + N + jbase + t];
  float qz = Q[boff + 2 * N + jbase + t];

  for (int ch = 0; ch < nch; ++ch) {
    unsigned short hx = f2bf(qx), hy = f2bf(qy), hz = f2bf(qz);
    unsigned short lx = f2bf(qx - bf2f(hx)), ly = f2bf(qy - bf2f(hy)),
                   lz = f2bf(qz - bf2f(hz));
    float nq = fmaf(qz, qz, fmaf(qy, qy, qx * qx));
    unsigned short nh = f2bf(nq);
    float r1 = nq - bf2f(nh);
    unsigned short nm = f2bf(r1);
    unsigned short nl = f2bf(r1 - bf2f(nm));
    uint4 b0s = make_uint4(pk(hx, hy), pk(hz, hx), pk(hy, hz), pk(lx, ly));
    uint4 b1s = make_uint4(pk(lz, lx), pk(ly, lz), pk(nh, nm), pk(nl, 0));

    __syncthreads();  // previous chunk fully consumed
    sB[0][t] = b0s;
    sB[1][t] = b1s;
    {  // prefetch next chunk's q
      int jn = (ch + 1 < nch) ? (jbase + (ch + 1) * TJQ + t) : (jbase + t);
      qx = Q[boff + jn];
      qy = Q[boff + N + jn];
      qz = Q[boff + 2 * N + jn];
    }
    __syncthreads();

#pragma unroll
    for (int jt = 0; jt < TJQ / MT; jt += 2) {
      FragU ba, bb;
      ba.u = sB[g][(jt + 0) * MT + m];
      bb.u = sB[g][(jt + 1) * MT + m];
      f32x16 d0, d1;
      MFMA2(d0, d1, af0, ba.s, bb.s, zc);
#pragma unroll
      for (int r = 0; r < 16; ++r) MIN3(run0[r], d0[r], d1[r]);
      f32x16 d2, d3;
      MFMA2(d2, d3, af1, ba.s, bb.s, zc);
#pragma unroll
      for (int r = 0; r < 16; ++r) MIN3(run1[r], d2[r], d3[r]);
    }
  }

  // ---- epilogue: min across 32 cols, add |p|^2, atomicMin ----
  // C/D layout (m74/m101): col=lane&31, row=(reg&3)+8*(reg>>2)+4*(lane>>5)
#pragma unroll
  for (int r = 0; r < 16; ++r) {
    float v0 = run0[r], v1 = run1[r];
#pragma unroll
    for (int sh = 1; sh <= 16; sh <<= 1) {
      v0 = fminf(v0, __shfl_xor(v0, sh));
      v1 = fminf(v1, __shfl_xor(v1, sh));
    }
    if (m == 0) {
      int row = (r & 3) + 8 * (r >> 2) + 4 * g;
      int il0 = w * (MT * IA) + row;
      int il1 = il0 + MT;
      atomicMin(&um[ib0 + il0], fmap(v0 + sNP[il0]));
      atomicMin(&um[ib0 + il1], fmap(v1 + sNP[il1]));
    }
  }
}

// Parallel final reduce: u holds complete squared distances (256 KB).
__global__ __launch_bounds__(256) void cl_reduce(
    const unsigned int* __restrict__ u, float* __restrict__ out, int total) {
  const int t = threadIdx.x;
  const uint4* __restrict__ u4 = (const uint4*)u;
  const int n4 = total / 4;
  const int gid = blockIdx.x * 256 + t;
  const int gstride = gridDim.x * 256;
  double s = 0.0;
  for (int i = gid; i < n4; i += gstride) {
    uint4 v = u4[i];
    s += (double)funmap(v.x) + (double)funmap(v.y) +
         (double)funmap(v.z) + (double)funmap(v.w);
  }
  for (int off = 32; off > 0; off >>= 1) s += __shfl_down(s, off, 64);
  __shared__ double sw[4];
  if ((t & 63) == 0) sw[t >> 6] = s;
  __syncthreads();
  if (t == 0) {
    double tot = sw[0] + sw[1] + sw[2] + sw[3];
    atomicAdd(out, (float)(tot / (double)total));
  }
}

extern "C" void kernel_launch(void* const* d_in, const int* in_sizes, int n_in,
                              void* d_out, int out_size, void* d_ws, size_t ws_size,
                              hipStream_t stream) {
  const float* in_pc = (const float*)d_in[0];
  const float* tgt_pc = (const float*)d_in[1];
  const int B = 2, N = 16384;
  unsigned int* u = (unsigned int*)d_ws;  // [2][B][N] uints = 256 KB
  float* out = (float*)d_out;

  hipMemsetAsync(u, 0xFF, (size_t)2 * B * N * sizeof(unsigned int), stream);
  hipMemsetAsync(out, 0, sizeof(float), stream);

  const int jslice = N / SJ;             // 4096
  dim3 grid(N / IB, SJ, 2 * B);          // (32,4,4) = 512 blocks x 512 thr
  cl_mfma<<<grid, dim3(BLK), 0, stream>>>(in_pc, tgt_pc, u, N, jslice, B);

  const int total = 2 * B * N;
  cl_reduce<<<dim3(16), dim3(256), 0, stream>>>(u, out, total);
}